// Round 1
// baseline (898.475 us; speedup 1.0000x reference)
//
#include <hip/hip_runtime.h>
#include <stdint.h>

#define FDIM 8192
#define KSEL 512
#define NT   256

// Order-preserving float -> uint key (larger key <=> larger float)
__device__ __forceinline__ unsigned keyOf(unsigned u) {
    return (u & 0x80000000u) ? ~u : (u | 0x80000000u);
}
__device__ __forceinline__ float valOf(unsigned key) {
    unsigned u = (key & 0x80000000u) ? (key ^ 0x80000000u) : ~key;
    return __uint_as_float(u);
}

__global__ __launch_bounds__(NT) void topk_mask_kernel(const float* __restrict__ x,
                                                       float* __restrict__ out) {
    __shared__ unsigned keys[FDIM];      // 32 KiB: order-preserving keys of this row
    __shared__ unsigned hist[256];
    __shared__ unsigned sfx[256];        // suffix sums of hist
    __shared__ unsigned s_need, s_prefix, s_eq;

    const int row = blockIdx.x;
    const int t   = threadIdx.x;
    const int lane = t & 63;

    const float4* xrow = (const float4*)(x + (size_t)row * FDIM);
    float4*       orow = (float4*)(out + (size_t)row * FDIM);
    uint4*        keys4 = (uint4*)keys;

    // ---- Pass 1: load row, transform to keys, stage in LDS (coalesced float4) ----
    for (int i = t; i < FDIM / 4; i += NT) {
        float4 v = xrow[i];
        uint4 k;
        k.x = keyOf(__float_as_uint(v.x));
        k.y = keyOf(__float_as_uint(v.y));
        k.z = keyOf(__float_as_uint(v.z));
        k.w = keyOf(__float_as_uint(v.w));
        keys4[i] = k;
    }
    if (t == 0) { s_need = KSEL; s_prefix = 0u; }
    __syncthreads();

    // ---- Radix select: find key of the KSEL-th largest element (MSB-first, 8b digits) ----
    for (int round = 0; round < 4; ++round) {
        const int shift = 24 - 8 * round;
        hist[t] = 0u;
        __syncthreads();
        const unsigned pref = s_prefix;
        const unsigned need = s_need;

        if (round == 0) {
            // Hot round: digits concentrate into few bins (sign+exponent byte of a
            // normal distribution). Ballot-aggregate per wave: lanes sharing a digit
            // elect a leader that adds popcount once, avoiding same-address atomic storms.
            for (int i = t; i < FDIM; i += NT) {           // 8192/256 = 32 exact iters, no divergence
                unsigned key = keys[i];
                unsigned dig = key >> 24;
                unsigned long long m = ~0ull;
                #pragma unroll
                for (int b = 0; b < 8; ++b) {
                    unsigned long long bb = __ballot((dig >> b) & 1u);
                    m &= ((dig >> b) & 1u) ? bb : ~bb;
                }
                int leader = __ffsll((long long)m) - 1;
                if (lane == leader)
                    atomicAdd(&hist[dig], (unsigned)__popcll(m));
            }
        } else {
            // Later rounds touch only the (small) prefix-matched subset.
            for (int i = t; i < FDIM; i += NT) {
                unsigned key = keys[i];
                if ((key >> (shift + 8)) == pref)
                    atomicAdd(&hist[(key >> shift) & 255u], 1u);
            }
        }
        __syncthreads();

        // suffix sum: sfx[b] = count of matched elements with digit >= b
        sfx[t] = hist[t];
        __syncthreads();
        for (int off = 1; off < 256; off <<= 1) {
            unsigned add = (t + off < 256) ? sfx[t + off] : 0u;
            __syncthreads();
            sfx[t] += add;
            __syncthreads();
        }

        const unsigned above = (t < 255) ? sfx[t + 1] : 0u;
        if (sfx[t] >= need && above < need) {   // exactly one thread (sfx is non-increasing)
            s_prefix = (pref << 8) | (unsigned)t;
            s_need   = need - above;            // how many of this digit's elements stay in top-K
            if (round == 3) s_eq = hist[t];     // total elements equal to the threshold key
        }
        __syncthreads();
    }

    const unsigned thresh = s_prefix;   // exact key of the KSEL-th largest
    const unsigned keepEq = s_need;     // # threshold-equal elements to keep (lowest indices)
    const unsigned eqCnt  = s_eq;
    const bool simple = (eqCnt == keepEq);  // common case: keep all equals

    // ---- Pass 2: write masked output from LDS keys (coalesced float4, no re-read of x) ----
    for (int i = t; i < FDIM / 4; i += NT) {
        uint4 k = keys4[i];
        float4 o;
        o.x = (k.x > thresh || (simple && k.x == thresh)) ? valOf(k.x) : 0.0f;
        o.y = (k.y > thresh || (simple && k.y == thresh)) ? valOf(k.y) : 0.0f;
        o.z = (k.z > thresh || (simple && k.z == thresh)) ? valOf(k.z) : 0.0f;
        o.w = (k.w > thresh || (simple && k.w == thresh)) ? valOf(k.w) : 0.0f;
        orow[i] = o;
    }

    // ---- Rare tie path: stable (lowest-index) selection among threshold equals ----
    if (!simple) {                      // block-uniform condition (shared values)
        __syncthreads();
        if (t == 0) {
            unsigned c = 0;
            const float v = valOf(thresh);
            for (int i = 0; i < FDIM && c < keepEq; ++i) {
                if (keys[i] == thresh) { out[(size_t)row * FDIM + i] = v; ++c; }
            }
        }
    }
}

extern "C" void kernel_launch(void* const* d_in, const int* in_sizes, int n_in,
                              void* d_out, int out_size, void* d_ws, size_t ws_size,
                              hipStream_t stream) {
    const float* x = (const float*)d_in[0];
    float* out = (float*)d_out;
    topk_mask_kernel<<<dim3(FDIM), dim3(NT), 0, stream>>>(x, out);
}

// Round 2
// 455.406 us; speedup vs baseline: 1.9729x; 1.9729x over previous
//
#include <hip/hip_runtime.h>
#include <stdint.h>

#define FDIM 8192
#define KSEL 512
#define NT   512
#define EPT  (FDIM / NT / 4)   // float4s per thread = 4 (16 scalar elements)

// Order-preserving float -> uint key (larger key <=> larger float)
__device__ __forceinline__ unsigned keyOf(unsigned u) {
    return (u & 0x80000000u) ? ~u : (u | 0x80000000u);
}
__device__ __forceinline__ float valOf(unsigned key) {
    unsigned u = (key & 0x80000000u) ? (key ^ 0x80000000u) : ~key;
    return __uint_as_float(u);
}

__global__ __launch_bounds__(NT) void topk_mask_kernel(const float* __restrict__ x,
                                                       float* __restrict__ out) {
    __shared__ unsigned hist[256];
    __shared__ unsigned s_prefix, s_need, s_sub;
    __shared__ unsigned s_tiecnt;
    __shared__ unsigned tiebuf[64];

    const int row  = blockIdx.x;
    const int t    = threadIdx.x;
    const int lane = t & 63;

    const float4* xrow = (const float4*)(x + (size_t)row * FDIM);
    float4*       orow = (float4*)(out + (size_t)row * FDIM);

    // ---- Load row into registers as order-preserving keys (coalesced float4) ----
    uint4 kreg[EPT];
    #pragma unroll
    for (int j = 0; j < EPT; ++j) {
        float4 v = xrow[j * NT + t];
        kreg[j].x = keyOf(__float_as_uint(v.x));
        kreg[j].y = keyOf(__float_as_uint(v.y));
        kreg[j].z = keyOf(__float_as_uint(v.z));
        kreg[j].w = keyOf(__float_as_uint(v.w));
    }
    if (t < 256) hist[t] = 0u;
    if (t == 0) { s_prefix = 0u; s_need = KSEL; s_tiecnt = 0u; }
    __syncthreads();

    // ---- Radix select over register-resident keys: 4 rounds of 8-bit digits ----
    for (int round = 0; round < 4; ++round) {
        const int shift = 24 - 8 * round;
        const unsigned pref = s_prefix;   // block-uniform

        if (round == 0) {
            // Hot round: digits concentrate into ~10 sign/exponent bins -> ballot-
            // aggregate per wave; one atomic per distinct digit per iteration.
            #pragma unroll
            for (int j = 0; j < EPT; ++j) {
                #pragma unroll
                for (int c = 0; c < 4; ++c) {
                    unsigned key = (&kreg[j].x)[c];
                    unsigned dig = key >> 24;
                    unsigned long long m = ~0ull;
                    #pragma unroll
                    for (int b = 0; b < 8; ++b) {
                        unsigned long long bb = __ballot((dig >> b) & 1u);
                        m &= ((dig >> b) & 1u) ? bb : ~bb;
                    }
                    if (lane == __ffsll((long long)m) - 1)
                        atomicAdd(&hist[dig], (unsigned)__popcll(m));
                }
            }
        } else {
            // Shrinking subset (8192 -> ~2200 -> ~10 -> ~1); digits near-uniform.
            #pragma unroll
            for (int j = 0; j < EPT; ++j) {
                #pragma unroll
                for (int c = 0; c < 4; ++c) {
                    unsigned key = (&kreg[j].x)[c];
                    if ((key >> (shift + 8)) == pref)
                        atomicAdd(&hist[(key >> shift) & 255u], 1u);
                }
            }
        }
        __syncthreads();

        // ---- Wave 0: suffix-scan 256 bins with shuffles, pick digit, zero hist ----
        if (t < 64) {
            const unsigned need = s_need;
            unsigned h0 = hist[4 * lane + 0];
            unsigned h1 = hist[4 * lane + 1];
            unsigned h2 = hist[4 * lane + 2];
            unsigned h3 = hist[4 * lane + 3];
            hist[4 * lane + 0] = 0u;   // ready for next round, no extra barrier
            hist[4 * lane + 1] = 0u;
            hist[4 * lane + 2] = 0u;
            hist[4 * lane + 3] = 0u;
            unsigned tot = h0 + h1 + h2 + h3;
            unsigned T = tot;          // inclusive suffix sum of lane totals
            #pragma unroll
            for (int off = 1; off < 64; off <<= 1) {
                unsigned y = __shfl_down(T, off);
                T += (lane + off < 64) ? y : 0u;
            }
            const unsigned beyond = T - tot;     // sum over lanes > this lane
            unsigned S3 = beyond + h3;
            unsigned S2 = S3 + h2;
            unsigned S1 = S2 + h1;
            unsigned S0 = S1 + h0;
            // exactly one (lane,k) satisfies: S >= need && S - h < need
            if (S0 >= need && S0 - h0 < need) {
                s_prefix = (pref << 8) | (unsigned)(4 * lane + 0);
                s_need = need - (S0 - h0); s_sub = h0;
            }
            if (S1 >= need && S1 - h1 < need) {
                s_prefix = (pref << 8) | (unsigned)(4 * lane + 1);
                s_need = need - (S1 - h1); s_sub = h1;
            }
            if (S2 >= need && S2 - h2 < need) {
                s_prefix = (pref << 8) | (unsigned)(4 * lane + 2);
                s_need = need - (S2 - h2); s_sub = h2;
            }
            if (S3 >= need && S3 - h3 < need) {
                s_prefix = (pref << 8) | (unsigned)(4 * lane + 3);
                s_need = need - (S3 - h3); s_sub = h3;
            }
        }
        __syncthreads();
    }

    const unsigned thresh = s_prefix;   // exact key of the KSEL-th largest
    const unsigned keepEq = s_need;     // # threshold-equal elements to keep
    const unsigned eqCnt  = s_sub;      // total threshold-equal elements
    const bool simple = (eqCnt == keepEq);

    // ---- Output pass straight from registers (coalesced float4 stores) ----
    if (simple) {
        #pragma unroll
        for (int j = 0; j < EPT; ++j) {
            uint4 k = kreg[j];
            float4 o;
            o.x = (k.x >= thresh) ? valOf(k.x) : 0.0f;
            o.y = (k.y >= thresh) ? valOf(k.y) : 0.0f;
            o.z = (k.z >= thresh) ? valOf(k.z) : 0.0f;
            o.w = (k.w >= thresh) ? valOf(k.w) : 0.0f;
            orow[j * NT + t] = o;
        }
    } else {
        #pragma unroll
        for (int j = 0; j < EPT; ++j) {
            uint4 k = kreg[j];
            float4 o;
            o.x = (k.x > thresh) ? valOf(k.x) : 0.0f;
            o.y = (k.y > thresh) ? valOf(k.y) : 0.0f;
            o.z = (k.z > thresh) ? valOf(k.z) : 0.0f;
            o.w = (k.w > thresh) ? valOf(k.w) : 0.0f;
            orow[j * NT + t] = o;
        }
        // ---- Rare tie path: stable (lowest-index) selection among equals ----
        #pragma unroll
        for (int j = 0; j < EPT; ++j) {
            #pragma unroll
            for (int c = 0; c < 4; ++c) {
                unsigned key = (&kreg[j].x)[c];
                if (key == thresh) {
                    unsigned slot = atomicAdd(&s_tiecnt, 1u);
                    if (slot < 64u) tiebuf[slot] = 4u * (unsigned)(j * NT + t) + (unsigned)c;
                }
            }
        }
        __syncthreads();
        if (t == 0) {
            const unsigned m = s_tiecnt;
            const float v = valOf(thresh);
            if (m <= 64u) {
                for (unsigned i = 0; i < m; ++i) {
                    unsigned idx = tiebuf[i], rank = 0;
                    for (unsigned q = 0; q < m; ++q) rank += (tiebuf[q] < idx);
                    if (rank < keepEq) out[(size_t)row * FDIM + idx] = v;
                }
            } else {
                unsigned c = 0;
                for (int i = 0; i < FDIM && c < keepEq; ++i) {
                    if (keyOf(__float_as_uint(x[(size_t)row * FDIM + i])) == thresh) {
                        out[(size_t)row * FDIM + i] = v; ++c;
                    }
                }
            }
        }
    }
}

extern "C" void kernel_launch(void* const* d_in, const int* in_sizes, int n_in,
                              void* d_out, int out_size, void* d_ws, size_t ws_size,
                              hipStream_t stream) {
    const float* x = (const float*)d_in[0];
    float* out = (float*)d_out;
    topk_mask_kernel<<<dim3(FDIM), dim3(NT), 0, stream>>>(x, out);
}

// Round 3
// 437.905 us; speedup vs baseline: 2.0518x; 1.0400x over previous
//
#include <hip/hip_runtime.h>
#include <stdint.h>

#define FDIM 8192
#define KSEL 512
#define NT   512
#define EPT  (FDIM / NT / 4)   // 4 float4s = 16 scalar elements per thread
#define NBIN 4096
#define NWAVE (NT / 64)

// Order-preserving float -> uint key (larger key <=> larger float)
__device__ __forceinline__ unsigned keyOf(unsigned u) {
    return (u & 0x80000000u) ? ~u : (u | 0x80000000u);
}
__device__ __forceinline__ float valOf(unsigned key) {
    unsigned u = (key & 0x80000000u) ? (key ^ 0x80000000u) : ~key;
    return __uint_as_float(u);
}

__global__ __launch_bounds__(NT) void topk_mask_kernel(const float* __restrict__ x,
                                                       float* __restrict__ out) {
    __shared__ unsigned hist[NBIN];        // 16 KiB: 12-bit-digit histogram
    __shared__ unsigned wtot[NWAVE];
    __shared__ unsigned s_prefix, s_need, s_sub, s_tiecnt;
    __shared__ unsigned tiebuf[64];

    const int row  = blockIdx.x;
    const int t    = threadIdx.x;
    const int lane = t & 63;
    const int wave = t >> 6;

    const float4* xrow = (const float4*)(x + (size_t)row * FDIM);
    float4*       orow = (float4*)(out + (size_t)row * FDIM);

    // ---- Load row into registers as order-preserving keys (coalesced float4) ----
    uint4 kreg[EPT];
    #pragma unroll
    for (int j = 0; j < EPT; ++j) {
        float4 v = xrow[j * NT + t];
        kreg[j].x = keyOf(__float_as_uint(v.x));
        kreg[j].y = keyOf(__float_as_uint(v.y));
        kreg[j].z = keyOf(__float_as_uint(v.z));
        kreg[j].w = keyOf(__float_as_uint(v.w));
    }
    #pragma unroll
    for (int i = t; i < NBIN; i += NT) hist[i] = 0u;
    if (t == 0) { s_prefix = 0u; s_need = KSEL; s_tiecnt = 0u; }
    __syncthreads();

    // ---- Radix select, 3 rounds of 12/12/8 bits. Counting on the DS pipe:
    //      4096 bins spread normal-data digits so same-address multiplicity ~2 (free).
    #pragma unroll
    for (int round = 0; round < 3; ++round) {
        const unsigned pref = s_prefix;   // block-uniform, stable until end-of-round
        const unsigned need = s_need;

        if (round == 0) {
            #pragma unroll
            for (int j = 0; j < EPT; ++j) {
                #pragma unroll
                for (int c = 0; c < 4; ++c) {
                    unsigned key = (&kreg[j].x)[c];
                    atomicAdd(&hist[key >> 20], 1u);
                }
            }
        } else if (round == 1) {
            #pragma unroll
            for (int j = 0; j < EPT; ++j) {
                #pragma unroll
                for (int c = 0; c < 4; ++c) {
                    unsigned key = (&kreg[j].x)[c];
                    if ((key >> 20) == pref)                       // ~290 of 8192 match
                        atomicAdd(&hist[(key >> 8) & 0xFFFu], 1u);
                }
            }
        } else {
            #pragma unroll
            for (int j = 0; j < EPT; ++j) {
                #pragma unroll
                for (int c = 0; c < 4; ++c) {
                    unsigned key = (&kreg[j].x)[c];
                    if ((key >> 8) == pref)                        // ~1-3 match
                        atomicAdd(&hist[key & 0xFFu], 1u);
                }
            }
        }
        __syncthreads();

        // ---- Hierarchical suffix-scan of 4096 bins: 8 bins/thread -> wave shfl
        //      scan -> 8 wave partials. Zero own bins in the same phase.
        const unsigned base = (unsigned)t * (NBIN / NT);
        unsigned sfx[9];                   // sfx[i] = sum of own bins [i..7]
        sfx[8] = 0u;
        #pragma unroll
        for (int i = 7; i >= 0; --i) sfx[i] = sfx[i + 1] + hist[base + i];
        #pragma unroll
        for (int i = 0; i < 8; ++i) hist[base + i] = 0u;   // ready for next round
        const unsigned tot = sfx[0];
        unsigned incl = tot;               // inclusive suffix over lanes >= this lane
        #pragma unroll
        for (int off = 1; off < 64; off <<= 1) {
            unsigned y = __shfl_down(incl, off);
            incl += (lane + off < 64) ? y : 0u;
        }
        if (lane == 0) wtot[wave] = incl;  // wave total
        __syncthreads();
        unsigned gb = incl - tot;          // beyond-this-thread within wave
        #pragma unroll
        for (int w = 0; w < NWAVE; ++w) gb += (w > wave) ? wtot[w] : 0u;

        // exactly one (thread, i) satisfies the straddle condition
        #pragma unroll
        for (int i = 0; i < 8; ++i) {
            unsigned S = gb + sfx[i];                  // count with digit >= base+i
            unsigned h = sfx[i] - sfx[i + 1];
            if (S >= need && S - h < need) {
                s_prefix = (round == 2) ? ((pref << 8) | (base + (unsigned)i))
                                        : ((pref << 12) | (base + (unsigned)i));
                s_need = need - (S - h);
                s_sub  = h;
            }
        }
        __syncthreads();
    }

    const unsigned thresh = s_prefix;   // exact key of the KSEL-th largest
    const unsigned keepEq = s_need;     // # threshold-equal elements to keep
    const unsigned eqCnt  = s_sub;      // total threshold-equal elements
    const bool simple = (eqCnt == keepEq);

    // ---- Output pass straight from registers (coalesced float4 stores) ----
    if (simple) {
        #pragma unroll
        for (int j = 0; j < EPT; ++j) {
            uint4 k = kreg[j];
            float4 o;
            o.x = (k.x >= thresh) ? valOf(k.x) : 0.0f;
            o.y = (k.y >= thresh) ? valOf(k.y) : 0.0f;
            o.z = (k.z >= thresh) ? valOf(k.z) : 0.0f;
            o.w = (k.w >= thresh) ? valOf(k.w) : 0.0f;
            orow[j * NT + t] = o;
        }
    } else {
        #pragma unroll
        for (int j = 0; j < EPT; ++j) {
            uint4 k = kreg[j];
            float4 o;
            o.x = (k.x > thresh) ? valOf(k.x) : 0.0f;
            o.y = (k.y > thresh) ? valOf(k.y) : 0.0f;
            o.z = (k.z > thresh) ? valOf(k.z) : 0.0f;
            o.w = (k.w > thresh) ? valOf(k.w) : 0.0f;
            orow[j * NT + t] = o;
        }
        // ---- Rare tie path: stable (lowest-index) selection among equals ----
        #pragma unroll
        for (int j = 0; j < EPT; ++j) {
            #pragma unroll
            for (int c = 0; c < 4; ++c) {
                unsigned key = (&kreg[j].x)[c];
                if (key == thresh) {
                    unsigned slot = atomicAdd(&s_tiecnt, 1u);
                    if (slot < 64u) tiebuf[slot] = 4u * (unsigned)(j * NT + t) + (unsigned)c;
                }
            }
        }
        __syncthreads();
        if (t == 0) {
            const unsigned m = s_tiecnt;
            const float v = valOf(thresh);
            if (m <= 64u) {
                for (unsigned i = 0; i < m; ++i) {
                    unsigned idx = tiebuf[i], rank = 0;
                    for (unsigned q = 0; q < m; ++q) rank += (tiebuf[q] < idx);
                    if (rank < keepEq) out[(size_t)row * FDIM + idx] = v;
                }
            } else {
                unsigned c = 0;
                for (int i = 0; i < FDIM && c < keepEq; ++i) {
                    if (keyOf(__float_as_uint(x[(size_t)row * FDIM + i])) == thresh) {
                        out[(size_t)row * FDIM + i] = v; ++c;
                    }
                }
            }
        }
    }
}

extern "C" void kernel_launch(void* const* d_in, const int* in_sizes, int n_in,
                              void* d_out, int out_size, void* d_ws, size_t ws_size,
                              hipStream_t stream) {
    const float* x = (const float*)d_in[0];
    float* out = (float*)d_out;
    topk_mask_kernel<<<dim3(FDIM), dim3(NT), 0, stream>>>(x, out);
}